// Round 2
// baseline (346.078 us; speedup 1.0000x reference)
//
#include <hip/hip_runtime.h>
#include <stdint.h>

#define N_ANCH 4096
#define NCLS 8
#define CN (N_ANCH * NCLS)
#define SCORE_TH 0.5f
#define IOU_TH 0.5f
#define KSEL 11
#define MAX_DET 100
#define CAND_CAP 4096
#define TILE 256
#define TPC (N_ANCH / TILE)          // 16
#define NTRI (TPC * (TPC + 1) / 2)   // 136 triangular tiles per class
#define GRID 256

struct Params {
    const float* boxes; const float* cls; const float* poses; const float* conf;
    float4* boxesT; float* areaT; float* scoresT; float* confT;
    int* validList; int* mVal; int* rep; int* surv;
    int* sel; int* count_g; float* cand; int* hist;
    int* blockCnt; int* gcnt; int* minRank; int* bar; float* out;
};

__device__ __forceinline__ float iou_f(float4 a, float areaA, float4 b, float areaB) {
    float x1 = fmaxf(a.x, b.x);
    float y1 = fmaxf(a.y, b.y);
    float x2 = fminf(a.z, b.z);
    float y2 = fminf(a.w, b.w);
    float wid = x2 - x1 + 1.0f;
    float hei = y2 - y1 + 1.0f;
    float inter = wid * hei;
    float den = areaA + areaB - inter;
    float ov = (den == 0.0f) ? 0.0f : (inter / den);
    if (wid <= 0.0f || hei <= 0.0f) ov = 0.0f;
    return ov;
}

// Software grid barrier: generation-based, device (agent) scope.
// bar[0] = arrival count, bar[16] = generation (separate cachelines).
// Safe because GRID=256 blocks <= 256 CUs x 2 blocks/CU capacity -> all resident.
__device__ __forceinline__ void gbar(int* bar) {
    __syncthreads();
    if (threadIdx.x == 0) {
        __threadfence();  // make this block's prior writes device-visible
        int g = __hip_atomic_load(&bar[16], __ATOMIC_RELAXED, __HIP_MEMORY_SCOPE_AGENT);
        int prev = __hip_atomic_fetch_add(&bar[0], 1, __ATOMIC_ACQ_REL, __HIP_MEMORY_SCOPE_AGENT);
        if (prev == GRID - 1) {
            __hip_atomic_store(&bar[0], 0, __ATOMIC_RELAXED, __HIP_MEMORY_SCOPE_AGENT);
            __hip_atomic_fetch_add(&bar[16], 1, __ATOMIC_RELEASE, __HIP_MEMORY_SCOPE_AGENT);
        } else {
            while (__hip_atomic_load(&bar[16], __ATOMIC_ACQUIRE, __HIP_MEMORY_SCOPE_AGENT) == g) {
                __builtin_amdgcn_s_sleep(2);
            }
        }
        __threadfence();
    }
    __syncthreads();
}

__global__ void __launch_bounds__(256, 2) fused(Params p) {
    const int bid = blockIdx.x;
    const int tid = threadIdx.x;
    const int lane = tid & 63, w = tid >> 6;

    __shared__ __align__(16) unsigned char SMEM[32768];
    __shared__ int s_misc[8];
    __shared__ int s_ksel[KSEL];
    __shared__ unsigned long long s_red[5];

    // ---- Phase 1 || 2: blocks 0..7 build per-class valid lists from raw cls;
    //                    blocks 8..255 transpose/prep + init surv/minRank/hist/gcnt.
    if (bid < NCLS) {
        int c = bid;
        unsigned long long* smask = (unsigned long long*)SMEM;  // [16][4]
        int* sbase = (int*)(SMEM + 512);                        // [16]
        for (int ch = 0; ch < 16; ch++) {
            int n = ch * 256 + tid;
            int flag = (p.cls[n * NCLS + c] > SCORE_TH) ? 1 : 0;
            unsigned long long m = __ballot(flag);
            if (lane == 0) smask[ch * 4 + w] = m;
        }
        __syncthreads();
        if (tid == 0) {
            int run = 0;
            for (int ch = 0; ch < 16; ch++) {
                sbase[ch] = run;
                run += __popcll(smask[ch * 4]) + __popcll(smask[ch * 4 + 1]) +
                       __popcll(smask[ch * 4 + 2]) + __popcll(smask[ch * 4 + 3]);
            }
            p.mVal[c] = run;
        }
        __syncthreads();
        for (int ch = 0; ch < 16; ch++) {
            unsigned long long m = smask[ch * 4 + w];
            if ((m >> lane) & 1ull) {
                int rank = __popcll(m & ((1ull << lane) - 1ull));
                int wb = 0;
                for (int i = 0; i < w; i++) wb += __popcll(smask[ch * 4 + i]);
                p.validList[c * N_ANCH + sbase[ch] + wb + rank] = ch * 256 + tid;
            }
        }
    } else {
        for (int t = (bid - NCLS) * 256 + tid; t < CN; t += (GRID - NCLS) * 256) {
            int n = t >> 3;   // anchor
            int c = t & 7;    // class
            int q = c * N_ANCH + n;
            p.scoresT[q] = p.cls[t];
            p.confT[q] = p.conf[t];
            float4 b = reinterpret_cast<const float4*>(p.boxes)[t];
            p.boxesT[q] = b;
            p.areaT[q] = (b.z - b.x + 1.0f) * (b.w - b.y + 1.0f);
            p.surv[t] = 0;
            p.minRank[t] = 0x7FFFFFFF;
        }
        int gt = (bid - NCLS) * 256 + tid;
        if (gt < 1024) p.hist[gt] = 0;
        if (gt == 1024) *p.gcnt = 0;
    }
    gbar(p.bar);

    // ---- Phase 3: triangular tiled rep-matrix (min-rank scan) ----------------
    for (int job = bid; job < NCLS * NTRI; job += GRID) {
        int c = job / NTRI;
        int t = job - c * NTRI;
        int ci = (int)((sqrtf(8.0f * (float)t + 1.0f) - 1.0f) * 0.5f);
        while ((ci + 1) * (ci + 2) / 2 <= t) ci++;
        while (ci * (ci + 1) / 2 > t) ci--;
        int cj = t - ci * (ci + 1) / 2;
        int mc = p.mVal[c];
        int ib = ci * TILE, jb = cj * TILE;
        if (ib >= mc || jb >= mc) continue;   // uniform across block
        int cbase = c << 12;
        const int* vl = p.validList + cbase;
        float4* sB = (float4*)SMEM;               // 256 * 16 B
        float* sA = (float*)(SMEM + TILE * 16);   // 256 * 4 B
        if (jb + tid < mc) {
            int vj = vl[jb + tid];
            sB[tid] = p.boxesT[cbase + vj];
            sA[tid] = p.areaT[cbase + vj];
        }
        __syncthreads();
        int i = ib + tid;
        if (i < mc) {
            int k = vl[i];
            float4 bk = p.boxesT[cbase + k];
            float ak = p.areaT[cbase + k];
            int limit = min(TILE, mc - jb);
            if (ci == cj) limit = min(limit, tid);  // strictly j-rank < i-rank
            int lmin = 0x7FFFFFFF;
            #pragma unroll 4
            for (int r = 0; r < limit; r++) {
                float ov = iou_f(bk, ak, sB[r], sA[r]);
                if (ov > IOU_TH && r < lmin) lmin = r;
            }
            if (lmin != 0x7FFFFFFF) atomicMin(&p.minRank[cbase + i], jb + lmin);
        }
        __syncthreads();
    }
    gbar(p.bar);

    // ---- Phase 4: finalize rep + surv ----------------------------------------
    for (int t = bid * 256 + tid; t < CN; t += GRID * 256) {
        int c = t >> 12;
        int i = t & (N_ANCH - 1);
        int mc = p.mVal[c];
        if (i >= mc) continue;
        int cbase = c << 12;
        const int* vl = p.validList + cbase;
        int k = vl[i];
        int mr = p.minRank[t];
        if (mr > i) mr = i;  // self
        int j = vl[mr];
        p.rep[cbase + k] = j;
        if (mr < i) {
            float ov = iou_f(p.boxesT[cbase + k], p.areaT[cbase + k],
                             p.boxesT[cbase + j], p.areaT[cbase + j]);
            float bcv = (1.0f - ov) * p.confT[cbase + k];
            if (bcv != 0.0f) p.surv[cbase + j] = 1;  // benign same-value race
        }
    }
    gbar(p.bar);

    // ---- Phase 5: per-chunk survivor counts + score histogram ----------------
    if (bid < CN / 256) {
        int q = bid * 256 + tid;
        int flag = p.surv[q] != 0;
        unsigned long long mask = __ballot(flag);
        if (lane == 0) s_misc[4 + w] = __popcll(mask);
        if (flag) {
            unsigned bits = __float_as_uint(p.scoresT[q]);
            int bb = (int)((bits - 0x3F000000u) >> 13);
            int bkt = bb < 0 ? 0 : (bb > 1023 ? 1023 : bb);
            atomicAdd(&p.hist[bkt], 1);
        }
        __syncthreads();
        if (tid == 0) p.blockCnt[bid] = s_misc[4] + s_misc[5] + s_misc[6] + s_misc[7];
    }
    gbar(p.bar);

    // ---- Phase 6: redundant prefix + threshold, ordered gather ---------------
    if (bid < CN / 256) {
        int* sCnt = (int*)SMEM;            // [128]
        int* sSfx = (int*)(SMEM + 512);    // [256]
        if (tid == 0) s_misc[0] = 0;       // thrB
        if (tid < 128) sCnt[tid] = p.blockCnt[tid];
        int part = p.hist[4 * tid] + p.hist[4 * tid + 1] +
                   p.hist[4 * tid + 2] + p.hist[4 * tid + 3];
        sSfx[tid] = part;
        __syncthreads();
        if (tid == 0) {
            int run = 0, myoff = 0;
            for (int i = 0; i < 128; i++) {
                if (i == bid) myoff = run;
                run += sCnt[i];
            }
            s_misc[1] = run;    // count
            s_misc[2] = myoff;  // this chunk's base offset
            if (bid == 0) *p.count_g = run;
            int run2 = 0;
            for (int i = 255; i >= 0; i--) { int v = sSfx[i]; sSfx[i] = run2; run2 += v; }
        }
        __syncthreads();
        int count = s_misc[1];
        int target = count < MAX_DET ? count : MAX_DET;
        int S = sSfx[tid];
        int found = -1;
        for (int b = 4 * tid + 3; b >= 4 * tid; b--) {
            S += p.hist[b];
            if (found < 0 && S >= target) found = b;
        }
        if (found >= 0) atomicMax(&s_misc[0], found);
        __syncthreads();
        int t0 = s_misc[0];
        // ordered gather
        int q = bid * 256 + tid;
        int flag = p.surv[q] != 0;
        unsigned long long mask = __ballot(flag);
        if (lane == 0) s_misc[4 + w] = __popcll(mask);
        __syncthreads();
        int rank = __popcll(mask & ((1ull << lane) - 1ull));
        int wbase = 0;
        for (int i = 0; i < w; i++) wbase += s_misc[4 + i];
        int idx = s_misc[2] + wbase + rank;
        if (flag && idx < MAX_DET) p.sel[idx] = q;
        if (flag) {
            unsigned bits = __float_as_uint(p.scoresT[q]);
            int bb = (int)((bits - 0x3F000000u) >> 13);
            int bkt = bb < 0 ? 0 : (bb > 1023 ? 1023 : bb);
            if (bkt >= t0) {
                int id = atomicAdd(p.gcnt, 1);
                if (id < CAND_CAP) p.cand[id] = p.scoresT[q];
            }
        }
    }
    gbar(p.bar);

    // ---- Phase 7: sort (block 0) || per-slot output (blocks 1..100) ----------
    if (bid == 0) {
        float* s = (float*)SMEM;  // up to 4096 floats
        int cc = *p.gcnt; if (cc > CAND_CAP) cc = CAND_CAP;
        int count = *p.count_g;
        int n = 128; while (n < cc) n <<= 1;
        for (int i = tid; i < n; i += 256) s[i] = (i < cc) ? -p.cand[i] : 1e38f;
        __syncthreads();
        for (int kk = 2; kk <= n; kk <<= 1) {
            for (int jj = kk >> 1; jj > 0; jj >>= 1) {
                for (int i = tid; i < n; i += 256) {
                    int ixj = i ^ jj;
                    if (ixj > i) {
                        float a = s[i], b2 = s[ixj];
                        bool up = ((i & kk) == 0);
                        if (up ? (a > b2) : (a < b2)) { s[i] = b2; s[ixj] = a; }
                    }
                }
                __syncthreads();
            }
        }
        if (tid < MAX_DET) p.out[tid] = (tid < count) ? -s[tid] : -1.0f;
    } else if (bid <= MAX_DET) {
        int s = bid - 1;
        int count = *p.count_g;
        if (s >= count) {
            if (tid == 0) { p.out[100 + s] = -1.0f; p.out[1400 + s] = -1.0f; }
            if (tid < 12) p.out[200 + s * 12 + tid] = -1.0f;
            if (tid >= 16 && tid < 20) p.out[1500 + s * 4 + (tid - 16)] = -1.0f;
        } else {
            int sp = p.sel[s];
            int c = sp >> 12;
            int r = sp & (N_ANCH - 1);
            unsigned long long* keyArr = (unsigned long long*)SMEM;  // 4096 * 8 B
            if (tid == 0) s_misc[0] = 0;  // nm
            __syncthreads();
            float4 br = p.boxesT[(c << 12) + r];
            float ar = p.areaT[(c << 12) + r];
            int mc = p.mVal[c];
            for (int i = tid; i < mc; i += 256) {
                int k = p.validList[(c << 12) + i];
                if (k != r && p.rep[(c << 12) + k] == r) {
                    float ov = iou_f(br, ar, p.boxesT[(c << 12) + k], p.areaT[(c << 12) + k]);
                    float bcv = (1.0f - ov) * p.confT[(c << 12) + k];
                    if (bcv != 0.0f) {
                        int id = atomicAdd(&s_misc[0], 1);
                        keyArr[id] = ((unsigned long long)__float_as_uint(bcv) << 32) | (unsigned)k;
                    }
                }
            }
            __syncthreads();
            int nm = s_misc[0];
            int dn = nm < KSEL ? nm : KSEL;
            unsigned long long lastBest = ~0ull;
            for (int j = 0; j < dn; j++) {
                unsigned long long bk = ~0ull;
                for (int i = tid; i < nm; i += 256) {
                    unsigned long long v = keyArr[i];
                    if (v == lastBest) { keyArr[i] = ~0ull; v = ~0ull; }
                    if (v < bk) bk = v;
                }
                for (int off = 32; off > 0; off >>= 1) {
                    unsigned long long o = __shfl_down(bk, off);
                    if (o < bk) bk = o;
                }
                if (lane == 0) s_red[w] = bk;
                __syncthreads();
                if (tid == 0) {
                    unsigned long long B = s_red[0];
                    for (int q2 = 1; q2 < 4; q2++) if (s_red[q2] < B) B = s_red[q2];
                    s_red[4] = B;
                    s_ksel[j] = (int)(B & 0xFFFFFFFFull);
                }
                __syncthreads();
                lastBest = s_red[4];
            }
            float fdn = (float)(dn > 0 ? dn : 1);
            if (tid < 12) {
                float ssum = 0.0f;
                for (int j = 0; j < dn; j++) {
                    int k = s_ksel[j];
                    ssum += p.poses[(k * 8 + c) * 12 + tid];
                }
                p.out[200 + s * 12 + tid] = ssum / fdn;
            } else if (tid < 16) {
                int d = tid - 12;
                float ssum = 0.0f;
                for (int j = 0; j < dn; j++) {
                    int k = s_ksel[j];
                    const float* bb2 = (const float*)&p.boxesT[(c << 12) + k];
                    ssum += bb2[d];
                }
                p.out[1500 + s * 4 + d] = ssum / fdn;
            } else if (tid == 16) {
                p.out[100 + s] = (float)c;
            } else if (tid == 17) {
                p.out[1400 + s] = (float)r;
            }
        }
    }
}

extern "C" void kernel_launch(void* const* d_in, const int* in_sizes, int n_in,
                              void* d_out, int out_size, void* d_ws, size_t ws_size,
                              hipStream_t stream) {
    const float* boxes = (const float*)d_in[1];
    const float* cls   = (const float*)d_in[2];
    const float* poses = (const float*)d_in[3];
    const float* conf  = (const float*)d_in[4];
    float* out = (float*)d_out;

    char* ws = (char*)d_ws;
    size_t off = 0;
    auto alloc = [&](size_t bytes) {
        void* pp = ws + off;
        off += (bytes + 255) & ~(size_t)255;
        return pp;
    };
    Params hp;
    hp.boxes = boxes; hp.cls = cls; hp.poses = poses; hp.conf = conf;
    hp.bar       = (int*)alloc(128);           // barrier state FIRST (memset below)
    hp.boxesT    = (float4*)alloc(CN * sizeof(float4));
    hp.areaT     = (float*)alloc(CN * sizeof(float));
    hp.scoresT   = (float*)alloc(CN * sizeof(float));
    hp.confT     = (float*)alloc(CN * sizeof(float));
    hp.validList = (int*)alloc(CN * sizeof(int));
    hp.mVal      = (int*)alloc(64);
    hp.rep       = (int*)alloc(CN * sizeof(int));
    hp.surv      = (int*)alloc(CN * sizeof(int));
    hp.sel       = (int*)alloc(MAX_DET * sizeof(int));
    hp.count_g   = (int*)alloc(64);
    hp.cand      = (float*)alloc(CAND_CAP * sizeof(float));
    hp.hist      = (int*)alloc(1024 * sizeof(int));
    hp.blockCnt  = (int*)alloc(128 * sizeof(int));
    hp.gcnt      = (int*)alloc(64);
    hp.minRank   = (int*)alloc(CN * sizeof(int));
    hp.out = out;

    hipMemsetAsync(hp.bar, 0, 128, stream);
    fused<<<GRID, 256, 0, stream>>>(hp);
}

// Round 3
// 286.568 us; speedup vs baseline: 1.2077x; 1.2077x over previous
//
#include <hip/hip_runtime.h>
#include <stdint.h>

#define N_ANCH 4096
#define NCLS 8
#define CN (N_ANCH * NCLS)
#define SCORE_TH 0.5f
#define IOU_TH 0.5f
#define KSEL 11
#define MAX_DET 100
#define CAND_CAP 4096
#define TILE 256
#define TPC (N_ANCH / TILE)          // 16
#define NTRI (TPC * (TPC + 1) / 2)   // 136 triangular tiles per class
#define GRID 256

struct Params {
    const float* boxes; const float* cls; const float* poses; const float* conf;
    float4* boxesT; float* areaT; float* scoresT; float* confT;
    int* validList; int* mVal; int* rep; int* surv;
    int* sel; int* count_g; float* cand; int* hist;
    int* blockCnt; int* gcnt; int* minRank; int* bar; float* out;
};

__device__ __forceinline__ float iou_f(float4 a, float areaA, float4 b, float areaB) {
    float x1 = fmaxf(a.x, b.x);
    float y1 = fmaxf(a.y, b.y);
    float x2 = fminf(a.z, b.z);
    float y2 = fminf(a.w, b.w);
    float wid = x2 - x1 + 1.0f;
    float hei = y2 - y1 + 1.0f;
    float inter = wid * hei;
    float den = areaA + areaB - inter;
    float ov = (den == 0.0f) ? 0.0f : (inter / den);
    if (wid <= 0.0f || hei <= 0.0f) ov = 0.0f;
    return ov;
}

// Contention-free software grid barrier.
// bar[0..255]   : per-block arrival slots (monotonic generation values)
// bar[256+32*g] : 8 replicated generation lines (g = bid & 7), 128 B apart
// No RMW contention: arrivals are plain release stores to distinct words.
// Block 0 detects (256 threads poll one slot each, relaxed) and publishes.
// Pollers poll their replica relaxed; ONE acquire fence after observing.
// Safe: GRID=256 blocks <= 256 CUs (LDS 33 KB -> 4/CU; 52 VGPR -> co-resident).
__device__ __forceinline__ void gbar(int* bar, int k) {
    __syncthreads();
    __threadfence();  // release: push this block's phase writes to coherence point
    if (threadIdx.x == 0) {
        __hip_atomic_store(&bar[blockIdx.x], k, __ATOMIC_RELEASE, __HIP_MEMORY_SCOPE_AGENT);
    }
    if (blockIdx.x == 0) {
        int t = threadIdx.x;
        while (__hip_atomic_load(&bar[t], __ATOMIC_RELAXED, __HIP_MEMORY_SCOPE_AGENT) < k) {
            __builtin_amdgcn_s_sleep(4);
        }
        __syncthreads();
        if (t < 8) {
            __threadfence();
            __hip_atomic_store(&bar[256 + t * 32], k, __ATOMIC_RELEASE, __HIP_MEMORY_SCOPE_AGENT);
        }
    } else {
        if (threadIdx.x == 0) {
            int* gen = &bar[256 + (blockIdx.x & 7) * 32];
            while (__hip_atomic_load(gen, __ATOMIC_RELAXED, __HIP_MEMORY_SCOPE_AGENT) < k) {
                __builtin_amdgcn_s_sleep(8);
            }
        }
    }
    __syncthreads();
    __threadfence();  // acquire: invalidate stale L1/L2 before reading others' data
    __syncthreads();
}

__global__ void __launch_bounds__(256, 2) fused(Params p) {
    const int bid = blockIdx.x;
    const int tid = threadIdx.x;
    const int lane = tid & 63, w = tid >> 6;

    __shared__ __align__(16) unsigned char SMEM[32768];
    __shared__ int s_misc[8];
    __shared__ int s_ksel[KSEL];
    __shared__ unsigned long long s_red[5];

    // ---- Phase 1 || 2: blocks 0..7 build per-class valid lists from raw cls;
    //                    blocks 8..255 transpose/prep + init counters.
    if (bid < NCLS) {
        int c = bid;
        unsigned long long* smask = (unsigned long long*)SMEM;  // [16][4]
        int* sbase = (int*)(SMEM + 512);                        // [16]
        for (int ch = 0; ch < 16; ch++) {
            int n = ch * 256 + tid;
            int flag = (p.cls[n * NCLS + c] > SCORE_TH) ? 1 : 0;
            unsigned long long m = __ballot(flag);
            if (lane == 0) smask[ch * 4 + w] = m;
        }
        __syncthreads();
        if (tid == 0) {
            int run = 0;
            for (int ch = 0; ch < 16; ch++) {
                sbase[ch] = run;
                run += __popcll(smask[ch * 4]) + __popcll(smask[ch * 4 + 1]) +
                       __popcll(smask[ch * 4 + 2]) + __popcll(smask[ch * 4 + 3]);
            }
            p.mVal[c] = run;
        }
        __syncthreads();
        for (int ch = 0; ch < 16; ch++) {
            unsigned long long m = smask[ch * 4 + w];
            if ((m >> lane) & 1ull) {
                int rank = __popcll(m & ((1ull << lane) - 1ull));
                int wb = 0;
                for (int i = 0; i < w; i++) wb += __popcll(smask[ch * 4 + i]);
                p.validList[c * N_ANCH + sbase[ch] + wb + rank] = ch * 256 + tid;
            }
        }
    } else {
        for (int t = (bid - NCLS) * 256 + tid; t < CN; t += (GRID - NCLS) * 256) {
            int n = t >> 3;   // anchor
            int c = t & 7;    // class
            int q = c * N_ANCH + n;
            p.scoresT[q] = p.cls[t];
            p.confT[q] = p.conf[t];
            float4 b = reinterpret_cast<const float4*>(p.boxes)[t];
            p.boxesT[q] = b;
            p.areaT[q] = (b.z - b.x + 1.0f) * (b.w - b.y + 1.0f);
            p.surv[t] = 0;
            p.minRank[t] = 0x7FFFFFFF;
        }
        int gt = (bid - NCLS) * 256 + tid;
        if (gt < 1024) p.hist[gt] = 0;
        if (gt >= 1024 && gt < 1152) p.blockCnt[gt - 1024] = 0;
        if (gt == 1152) *p.gcnt = 0;
    }
    gbar(p.bar, 1);

    // ---- Phase 3: triangular tiled rep-matrix (min-rank scan) ----------------
    for (int job = bid; job < NCLS * NTRI; job += GRID) {
        int c = job / NTRI;
        int t = job - c * NTRI;
        int ci = (int)((sqrtf(8.0f * (float)t + 1.0f) - 1.0f) * 0.5f);
        while ((ci + 1) * (ci + 2) / 2 <= t) ci++;
        while (ci * (ci + 1) / 2 > t) ci--;
        int cj = t - ci * (ci + 1) / 2;
        int mc = p.mVal[c];
        int ib = ci * TILE, jb = cj * TILE;
        if (ib >= mc || jb >= mc) continue;   // uniform across block
        int cbase = c << 12;
        const int* vl = p.validList + cbase;
        float4* sB = (float4*)SMEM;               // 256 * 16 B
        float* sA = (float*)(SMEM + TILE * 16);   // 256 * 4 B
        if (jb + tid < mc) {
            int vj = vl[jb + tid];
            sB[tid] = p.boxesT[cbase + vj];
            sA[tid] = p.areaT[cbase + vj];
        }
        __syncthreads();
        int i = ib + tid;
        if (i < mc) {
            int k = vl[i];
            float4 bk = p.boxesT[cbase + k];
            float ak = p.areaT[cbase + k];
            int limit = min(TILE, mc - jb);
            if (ci == cj) limit = min(limit, tid);  // strictly j-rank < i-rank
            int lmin = 0x7FFFFFFF;
            #pragma unroll 4
            for (int r = 0; r < limit; r++) {
                float ov = iou_f(bk, ak, sB[r], sA[r]);
                if (ov > IOU_TH && r < lmin) lmin = r;
            }
            if (lmin != 0x7FFFFFFF) atomicMin(&p.minRank[cbase + i], jb + lmin);
        }
        __syncthreads();
    }
    gbar(p.bar, 2);

    // ---- Phase 4: finalize rep + surv, first-setter counts + histogram -------
    for (int t = bid * 256 + tid; t < CN; t += GRID * 256) {
        int c = t >> 12;
        int i = t & (N_ANCH - 1);
        int mc = p.mVal[c];
        if (i >= mc) continue;
        int cbase = c << 12;
        const int* vl = p.validList + cbase;
        int k = vl[i];
        int mr = p.minRank[t];
        if (mr > i) mr = i;  // self
        int j = vl[mr];
        p.rep[cbase + k] = j;
        if (mr < i) {
            float ov = iou_f(p.boxesT[cbase + k], p.areaT[cbase + k],
                             p.boxesT[cbase + j], p.areaT[cbase + j]);
            float bcv = (1.0f - ov) * p.confT[cbase + k];
            if (bcv != 0.0f) {
                int old = atomicExch(&p.surv[cbase + j], 1);
                if (old == 0) {
                    int q = cbase + j;
                    atomicAdd(&p.blockCnt[q >> 8], 1);
                    unsigned bits = __float_as_uint(p.scoresT[q]);
                    int bb = (int)((bits - 0x3F000000u) >> 13);
                    int bkt = bb < 0 ? 0 : (bb > 1023 ? 1023 : bb);
                    atomicAdd(&p.hist[bkt], 1);
                }
            }
        }
    }
    gbar(p.bar, 3);

    // ---- Phase 6: redundant prefix + threshold, ordered gather ---------------
    if (bid < CN / 256) {
        int* sCnt = (int*)SMEM;            // [128]
        int* sSfx = (int*)(SMEM + 512);    // [256]
        if (tid == 0) s_misc[0] = 0;       // thrB
        if (tid < 128) sCnt[tid] = p.blockCnt[tid];
        int part = p.hist[4 * tid] + p.hist[4 * tid + 1] +
                   p.hist[4 * tid + 2] + p.hist[4 * tid + 3];
        sSfx[tid] = part;
        __syncthreads();
        if (tid == 0) {
            int run = 0, myoff = 0;
            for (int i = 0; i < 128; i++) {
                if (i == bid) myoff = run;
                run += sCnt[i];
            }
            s_misc[1] = run;    // count
            s_misc[2] = myoff;  // this chunk's base offset
            if (bid == 0) *p.count_g = run;
            int run2 = 0;
            for (int i = 255; i >= 0; i--) { int v = sSfx[i]; sSfx[i] = run2; run2 += v; }
        }
        __syncthreads();
        int count = s_misc[1];
        int target = count < MAX_DET ? count : MAX_DET;
        int S = sSfx[tid];
        int found = -1;
        for (int b = 4 * tid + 3; b >= 4 * tid; b--) {
            S += p.hist[b];
            if (found < 0 && S >= target) found = b;
        }
        if (found >= 0) atomicMax(&s_misc[0], found);
        __syncthreads();
        int t0 = s_misc[0];
        // ordered gather
        int q = bid * 256 + tid;
        int flag = p.surv[q] != 0;
        unsigned long long mask = __ballot(flag);
        if (lane == 0) s_misc[4 + w] = __popcll(mask);
        __syncthreads();
        int rank = __popcll(mask & ((1ull << lane) - 1ull));
        int wbase = 0;
        for (int i = 0; i < w; i++) wbase += s_misc[4 + i];
        int idx = s_misc[2] + wbase + rank;
        if (flag && idx < MAX_DET) p.sel[idx] = q;
        if (flag) {
            unsigned bits = __float_as_uint(p.scoresT[q]);
            int bb = (int)((bits - 0x3F000000u) >> 13);
            int bkt = bb < 0 ? 0 : (bb > 1023 ? 1023 : bb);
            if (bkt >= t0) {
                int id = atomicAdd(p.gcnt, 1);
                if (id < CAND_CAP) p.cand[id] = p.scoresT[q];
            }
        }
    }
    gbar(p.bar, 4);

    // ---- Phase 7: sort (block 0) || per-slot output (blocks 1..100) ----------
    if (bid == 0) {
        float* s = (float*)SMEM;  // up to 4096 floats
        int cc = *p.gcnt; if (cc > CAND_CAP) cc = CAND_CAP;
        int count = *p.count_g;
        int n = 128; while (n < cc) n <<= 1;
        for (int i = tid; i < n; i += 256) s[i] = (i < cc) ? -p.cand[i] : 1e38f;
        __syncthreads();
        for (int kk = 2; kk <= n; kk <<= 1) {
            for (int jj = kk >> 1; jj > 0; jj >>= 1) {
                for (int i = tid; i < n; i += 256) {
                    int ixj = i ^ jj;
                    if (ixj > i) {
                        float a = s[i], b2 = s[ixj];
                        bool up = ((i & kk) == 0);
                        if (up ? (a > b2) : (a < b2)) { s[i] = b2; s[ixj] = a; }
                    }
                }
                __syncthreads();
            }
        }
        if (tid < MAX_DET) p.out[tid] = (tid < count) ? -s[tid] : -1.0f;
    } else if (bid <= MAX_DET) {
        int s = bid - 1;
        int count = *p.count_g;
        if (s >= count) {
            if (tid == 0) { p.out[100 + s] = -1.0f; p.out[1400 + s] = -1.0f; }
            if (tid < 12) p.out[200 + s * 12 + tid] = -1.0f;
            if (tid >= 16 && tid < 20) p.out[1500 + s * 4 + (tid - 16)] = -1.0f;
        } else {
            int sp = p.sel[s];
            int c = sp >> 12;
            int r = sp & (N_ANCH - 1);
            unsigned long long* keyArr = (unsigned long long*)SMEM;  // 4096 * 8 B
            if (tid == 0) s_misc[0] = 0;  // nm
            __syncthreads();
            float4 br = p.boxesT[(c << 12) + r];
            float ar = p.areaT[(c << 12) + r];
            int mc = p.mVal[c];
            for (int i = tid; i < mc; i += 256) {
                int k = p.validList[(c << 12) + i];
                if (k != r && p.rep[(c << 12) + k] == r) {
                    float ov = iou_f(br, ar, p.boxesT[(c << 12) + k], p.areaT[(c << 12) + k]);
                    float bcv = (1.0f - ov) * p.confT[(c << 12) + k];
                    if (bcv != 0.0f) {
                        int id = atomicAdd(&s_misc[0], 1);
                        keyArr[id] = ((unsigned long long)__float_as_uint(bcv) << 32) | (unsigned)k;
                    }
                }
            }
            __syncthreads();
            int nm = s_misc[0];
            int dn = nm < KSEL ? nm : KSEL;
            unsigned long long lastBest = ~0ull;
            for (int j = 0; j < dn; j++) {
                unsigned long long bk = ~0ull;
                for (int i = tid; i < nm; i += 256) {
                    unsigned long long v = keyArr[i];
                    if (v == lastBest) { keyArr[i] = ~0ull; v = ~0ull; }
                    if (v < bk) bk = v;
                }
                for (int off = 32; off > 0; off >>= 1) {
                    unsigned long long o = __shfl_down(bk, off);
                    if (o < bk) bk = o;
                }
                if (lane == 0) s_red[w] = bk;
                __syncthreads();
                if (tid == 0) {
                    unsigned long long B = s_red[0];
                    for (int q2 = 1; q2 < 4; q2++) if (s_red[q2] < B) B = s_red[q2];
                    s_red[4] = B;
                    s_ksel[j] = (int)(B & 0xFFFFFFFFull);
                }
                __syncthreads();
                lastBest = s_red[4];
            }
            float fdn = (float)(dn > 0 ? dn : 1);
            if (tid < 12) {
                float ssum = 0.0f;
                for (int j = 0; j < dn; j++) {
                    int k = s_ksel[j];
                    ssum += p.poses[(k * 8 + c) * 12 + tid];
                }
                p.out[200 + s * 12 + tid] = ssum / fdn;
            } else if (tid < 16) {
                int d = tid - 12;
                float ssum = 0.0f;
                for (int j = 0; j < dn; j++) {
                    int k = s_ksel[j];
                    const float* bb2 = (const float*)&p.boxesT[(c << 12) + k];
                    ssum += bb2[d];
                }
                p.out[1500 + s * 4 + d] = ssum / fdn;
            } else if (tid == 16) {
                p.out[100 + s] = (float)c;
            } else if (tid == 17) {
                p.out[1400 + s] = (float)r;
            }
        }
    }
}

extern "C" void kernel_launch(void* const* d_in, const int* in_sizes, int n_in,
                              void* d_out, int out_size, void* d_ws, size_t ws_size,
                              hipStream_t stream) {
    const float* boxes = (const float*)d_in[1];
    const float* cls   = (const float*)d_in[2];
    const float* poses = (const float*)d_in[3];
    const float* conf  = (const float*)d_in[4];
    float* out = (float*)d_out;

    char* ws = (char*)d_ws;
    size_t off = 0;
    auto alloc = [&](size_t bytes) {
        void* pp = ws + off;
        off += (bytes + 255) & ~(size_t)255;
        return pp;
    };
    Params hp;
    hp.boxes = boxes; hp.cls = cls; hp.poses = poses; hp.conf = conf;
    hp.bar       = (int*)alloc(2048);          // barrier slots + gen replicas
    hp.boxesT    = (float4*)alloc(CN * sizeof(float4));
    hp.areaT     = (float*)alloc(CN * sizeof(float));
    hp.scoresT   = (float*)alloc(CN * sizeof(float));
    hp.confT     = (float*)alloc(CN * sizeof(float));
    hp.validList = (int*)alloc(CN * sizeof(int));
    hp.mVal      = (int*)alloc(64);
    hp.rep       = (int*)alloc(CN * sizeof(int));
    hp.surv      = (int*)alloc(CN * sizeof(int));
    hp.sel       = (int*)alloc(MAX_DET * sizeof(int));
    hp.count_g   = (int*)alloc(64);
    hp.cand      = (float*)alloc(CAND_CAP * sizeof(float));
    hp.hist      = (int*)alloc(1024 * sizeof(int));
    hp.blockCnt  = (int*)alloc(128 * sizeof(int));
    hp.gcnt      = (int*)alloc(64);
    hp.minRank   = (int*)alloc(CN * sizeof(int));
    hp.out = out;

    hipMemsetAsync(hp.bar, 0, 2048, stream);
    fused<<<GRID, 256, 0, stream>>>(hp);
}

// Round 6
// 199.083 us; speedup vs baseline: 1.7384x; 1.4394x over previous
//
#include <hip/hip_runtime.h>
#include <stdint.h>

#define N_ANCH 4096
#define NCLS 8
#define CN (N_ANCH * NCLS)
#define SCORE_TH 0.5f
#define IOU_TH 0.5f
#define KSEL 11
#define MAX_DET 100
#define CAND_CAP 4096
#define CHUNK 64                     // ranks per rep-block
#define NCHUNK (N_ANCH / CHUNK)      // 64 chunks per class

struct Params {
    const float* boxes; const float* cls; const float* poses; const float* conf;
    int* surv; int* hist; int* blockCnt; int* gcnt;     // zeroed by memset
    int* rep; int* sel; int* count_g; float* cand;
    float* out;
};

__device__ __forceinline__ float area_f(float4 b) {
    return (b.z - b.x + 1.0f) * (b.w - b.y + 1.0f);
}

__device__ __forceinline__ float iou_f(float4 a, float areaA, float4 b, float areaB) {
    float x1 = fmaxf(a.x, b.x);
    float y1 = fmaxf(a.y, b.y);
    float x2 = fminf(a.z, b.z);
    float y2 = fminf(a.w, b.w);
    float wid = x2 - x1 + 1.0f;
    float hei = y2 - y1 + 1.0f;
    float inter = wid * hei;
    float den = areaA + areaB - inter;
    float ov = (den == 0.0f) ? 0.0f : (inter / den);
    if (wid <= 0.0f || hei <= 0.0f) ov = 0.0f;
    return ov;
}

// kR: block = (class c, rank-chunk h). Rebuilds class-c valid-list prefix in LDS
// (ballot compact over raw cls), computes per-row min-rank match over all j<i
// (4 threads/row, per-quarter first-match, early break), then finalizes:
// rep[anchor], surv first-setter + blockCnt/hist counts. Self-contained.
__global__ void __launch_bounds__(256) kR(Params p) {
    const int bid = blockIdx.x;
    const int tid = threadIdx.x;
    const int lane = tid & 63, w = tid >> 6;
    const int c = bid >> 6;          // class
    const int h = bid & (NCHUNK - 1);
    const int base = h * CHUNK;
    const int need = base + CHUNK;   // valid-list entries required
    const int cbase = c << 12;

    __shared__ int vl[4096];
    __shared__ int wcnt[4];
    __shared__ int lmin[CHUNK];
    __shared__ float4 sB[256];
    __shared__ float sA[256];

    // ---- build valid-list prefix (ranks 0 .. min(run,need)) ----
    int run = 0;
    for (int ch = 0; ch < 16; ch++) {
        int a = ch * 256 + tid;
        int flag = (p.cls[a * 8 + c] > SCORE_TH) ? 1 : 0;
        unsigned long long m = __ballot(flag);
        if (lane == 0) wcnt[w] = __popcll(m);
        __syncthreads();
        int wb = run;
        for (int i = 0; i < w; i++) wb += wcnt[i];
        int tot = wcnt[0] + wcnt[1] + wcnt[2] + wcnt[3];
        if (flag) {
            int rank = __popcll(m & ((1ull << lane) - 1ull));
            vl[wb + rank] = a;
        }
        run += tot;
        __syncthreads();            // protect wcnt reuse
        if (run >= need) break;     // uniform
    }
    int mcap = run < need ? run : need;   // ranks available: [0, mcap)
    if (base >= mcap) return;             // no rows for this block (uniform)

    // ---- per-row state ----
    const float4* boxes4 = (const float4*)p.boxes;
    int rowi = base + (tid & (CHUNK - 1));   // my row rank
    int q4 = tid >> 6;                       // quarter 0..3
    bool haveRow = rowi < mcap;
    int kAnchor = 0; float4 bk; float ak = 0.0f;
    if (haveRow) {
        kAnchor = vl[rowi];
        bk = boxes4[kAnchor * 8 + c];
        ak = area_f(bk);
    }
    if (tid < CHUNK) lmin[tid] = 0x7FFFFFFF;

    // ---- j<i min-rank scan, tiles of 256 staged in LDS ----
    int Tmax = (mcap + 255) >> 8;
    bool qdone = false;
    for (int T = 0; T < Tmax; T++) {
        int jr = T * 256 + tid;
        if (jr < mcap) {
            int a = vl[jr];
            float4 b = boxes4[a * 8 + c];
            sB[tid] = b;
            sA[tid] = area_f(b);
        }
        __syncthreads();
        if (haveRow && !qdone) {
            int lo = q4 * 64;
            int hi = lo + 64;
            int cap = rowi - T * 256;   // local e must satisfy T*256+e < rowi
            if (cap < hi) hi = cap;
            for (int e = lo; e < hi; e++) {
                float ov = iou_f(bk, ak, sB[e], sA[e]);
                if (ov > IOU_TH) {
                    atomicMin(&lmin[tid & (CHUNK - 1)], T * 256 + e);
                    qdone = true;       // ascending ranges per quarter -> first = min
                    break;
                }
            }
        }
        __syncthreads();
    }

    // ---- finalize rows of this chunk ----
    if (tid < CHUNK) {
        int i = base + tid;
        if (i < mcap) {
            int mr = lmin[tid];
            int k = vl[i];
            if (mr < i) {
                int ja = vl[mr];
                p.rep[cbase + k] = ja;
                float4 bj = boxes4[ja * 8 + c];
                float ov = iou_f(boxes4[k * 8 + c], area_f(boxes4[k * 8 + c]), bj, area_f(bj));
                float bcv = (1.0f - ov) * p.conf[k * 8 + c];
                if (bcv != 0.0f) {
                    int old = atomicExch(&p.surv[cbase + ja], 1);
                    if (old == 0) {
                        int fq = cbase + ja;
                        atomicAdd(&p.blockCnt[fq >> 8], 1);
                        unsigned bits = __float_as_uint(p.cls[ja * 8 + c]);
                        int bb = (int)((bits - 0x3F000000u) >> 13);
                        int bkt = bb < 0 ? 0 : (bb > 1023 ? 1023 : bb);
                        atomicAdd(&p.hist[bkt], 1);
                    }
                }
            } else {
                p.rep[cbase + k] = k;   // self
            }
        }
    }
}

// kG: 128 blocks. Redundant chunk-prefix + histogram threshold, ordered
// sel-write of first 100 survivors (flat order), candidate score gather.
__global__ void __launch_bounds__(256) kG(Params p) {
    const int bid = blockIdx.x;
    const int tid = threadIdx.x;
    const int lane = tid & 63, w = tid >> 6;
    __shared__ int sCnt[128];
    __shared__ int sSfx[256];
    __shared__ int s_misc[8];

    if (tid == 0) s_misc[0] = 0;  // thrB
    if (tid < 128) sCnt[tid] = p.blockCnt[tid];
    int part = p.hist[4 * tid] + p.hist[4 * tid + 1] +
               p.hist[4 * tid + 2] + p.hist[4 * tid + 3];
    sSfx[tid] = part;
    __syncthreads();
    if (tid == 0) {
        int run = 0, myoff = 0;
        for (int i = 0; i < 128; i++) {
            if (i == bid) myoff = run;
            run += sCnt[i];
        }
        s_misc[1] = run;    // total survivor count
        s_misc[2] = myoff;  // this chunk's base offset
        if (bid == 0) *p.count_g = run;
        int run2 = 0;
        for (int i = 255; i >= 0; i--) { int v = sSfx[i]; sSfx[i] = run2; run2 += v; }
    }
    __syncthreads();
    int count = s_misc[1];
    int target = count < MAX_DET ? count : MAX_DET;
    int S = sSfx[tid];
    int found = -1;
    for (int b = 4 * tid + 3; b >= 4 * tid; b--) {
        S += p.hist[b];
        if (found < 0 && S >= target) found = b;
    }
    if (found >= 0) atomicMax(&s_misc[0], found);
    __syncthreads();
    int t0 = s_misc[0];

    // ordered gather
    int q = bid * 256 + tid;
    int c = q >> 12, n = q & (N_ANCH - 1);
    int flag = p.surv[q] != 0;
    unsigned long long mask = __ballot(flag);
    if (lane == 0) s_misc[4 + w] = __popcll(mask);
    __syncthreads();
    int rank = __popcll(mask & ((1ull << lane) - 1ull));
    int wbase = 0;
    for (int i = 0; i < w; i++) wbase += s_misc[4 + i];
    int idx = s_misc[2] + wbase + rank;
    if (flag && idx < MAX_DET) p.sel[idx] = q;
    if (flag) {
        float sc = p.cls[n * 8 + c];
        unsigned bits = __float_as_uint(sc);
        int bb = (int)((bits - 0x3F000000u) >> 13);
        int bkt = bb < 0 ? 0 : (bb > 1023 ? 1023 : bb);
        if (bkt >= t0) {
            int id = atomicAdd(p.gcnt, 1);
            if (id < CAND_CAP) p.cand[id] = sc;
        }
    }
}

// kO: block 0 = bitonic sort of candidate scores -> top-100 scores;
// blocks 1..100 = per-slot cluster gather + KSEL selection + averages.
__global__ void __launch_bounds__(256) kO(Params p) {
    const int bid = blockIdx.x;
    const int tid = threadIdx.x;
    const int lane = tid & 63, w = tid >> 6;
    __shared__ __align__(16) unsigned char SMEM[32768];
    __shared__ int s_misc[8];
    __shared__ int s_ksel[KSEL];
    __shared__ unsigned long long s_red[5];
    const float4* boxes4 = (const float4*)p.boxes;

    if (bid == 0) {
        float* s = (float*)SMEM;
        int cc = *p.gcnt; if (cc > CAND_CAP) cc = CAND_CAP;
        int count = *p.count_g;
        int n = 128; while (n < cc) n <<= 1;
        for (int i = tid; i < n; i += 256) s[i] = (i < cc) ? -p.cand[i] : 1e38f;
        __syncthreads();
        for (int kk = 2; kk <= n; kk <<= 1) {
            for (int jj = kk >> 1; jj > 0; jj >>= 1) {
                for (int i = tid; i < n; i += 256) {
                    int ixj = i ^ jj;
                    if (ixj > i) {
                        float a = s[i], b2 = s[ixj];
                        bool up = ((i & kk) == 0);
                        if (up ? (a > b2) : (a < b2)) { s[i] = b2; s[ixj] = a; }
                    }
                }
                __syncthreads();
            }
        }
        if (tid < MAX_DET) p.out[tid] = (tid < count) ? -s[tid] : -1.0f;
    } else {
        int s = bid - 1;
        int count = *p.count_g;
        if (s >= count) {
            if (tid == 0) { p.out[100 + s] = -1.0f; p.out[1400 + s] = -1.0f; }
            if (tid < 12) p.out[200 + s * 12 + tid] = -1.0f;
            if (tid >= 16 && tid < 20) p.out[1500 + s * 4 + (tid - 16)] = -1.0f;
        } else {
            int sp = p.sel[s];
            int c = sp >> 12;
            int r = sp & (N_ANCH - 1);
            int cbase = c << 12;
            unsigned long long* keyArr = (unsigned long long*)SMEM;  // 4096 x 8 B
            if (tid == 0) s_misc[0] = 0;  // nm
            __syncthreads();
            float4 br = boxes4[r * 8 + c];
            float ar = area_f(br);
            for (int k = tid; k < N_ANCH; k += 256) {
                if (k != r && p.cls[k * 8 + c] > SCORE_TH && p.rep[cbase + k] == r) {
                    float4 bkk = boxes4[k * 8 + c];
                    float ov = iou_f(br, ar, bkk, area_f(bkk));
                    float bcv = (1.0f - ov) * p.conf[k * 8 + c];
                    if (bcv != 0.0f) {
                        int id = atomicAdd(&s_misc[0], 1);
                        keyArr[id] = ((unsigned long long)__float_as_uint(bcv) << 32) | (unsigned)k;
                    }
                }
            }
            __syncthreads();
            int nm = s_misc[0];
            int dn = nm < KSEL ? nm : KSEL;
            unsigned long long lastBest = ~0ull;
            for (int j = 0; j < dn; j++) {
                unsigned long long bk = ~0ull;
                for (int i = tid; i < nm; i += 256) {
                    unsigned long long v = keyArr[i];
                    if (v == lastBest) { keyArr[i] = ~0ull; v = ~0ull; }
                    if (v < bk) bk = v;
                }
                for (int off = 32; off > 0; off >>= 1) {
                    unsigned long long o = __shfl_down(bk, off);
                    if (o < bk) bk = o;
                }
                if (lane == 0) s_red[w] = bk;
                __syncthreads();
                if (tid == 0) {
                    unsigned long long B = s_red[0];
                    for (int q2 = 1; q2 < 4; q2++) if (s_red[q2] < B) B = s_red[q2];
                    s_red[4] = B;
                    s_ksel[j] = (int)(B & 0xFFFFFFFFull);
                }
                __syncthreads();
                lastBest = s_red[4];
            }
            float fdn = (float)(dn > 0 ? dn : 1);
            if (tid < 12) {
                float ssum = 0.0f;
                for (int j = 0; j < dn; j++) {
                    int k = s_ksel[j];
                    ssum += p.poses[(k * 8 + c) * 12 + tid];
                }
                p.out[200 + s * 12 + tid] = ssum / fdn;
            } else if (tid < 16) {
                int d = tid - 12;
                float ssum = 0.0f;
                for (int j = 0; j < dn; j++) {
                    int k = s_ksel[j];
                    const float* bb2 = (const float*)&boxes4[k * 8 + c];
                    ssum += bb2[d];
                }
                p.out[1500 + s * 4 + d] = ssum / fdn;
            } else if (tid == 16) {
                p.out[100 + s] = (float)c;
            } else if (tid == 17) {
                p.out[1400 + s] = (float)r;
            }
        }
    }
}

extern "C" void kernel_launch(void* const* d_in, const int* in_sizes, int n_in,
                              void* d_out, int out_size, void* d_ws, size_t ws_size,
                              hipStream_t stream) {
    Params hp;
    hp.boxes = (const float*)d_in[1];
    hp.cls   = (const float*)d_in[2];
    hp.poses = (const float*)d_in[3];
    hp.conf  = (const float*)d_in[4];
    hp.out   = (float*)d_out;

    char* ws = (char*)d_ws;
    size_t off = 0;
    auto alloc = [&](size_t bytes) {
        void* pp = ws + off;
        off += (bytes + 255) & ~(size_t)255;
        return pp;
    };
    // zero-init region (one memset): surv, hist, blockCnt, gcnt
    hp.surv     = (int*)alloc(CN * sizeof(int));
    hp.hist     = (int*)alloc(1024 * sizeof(int));
    hp.blockCnt = (int*)alloc(128 * sizeof(int));
    hp.gcnt     = (int*)alloc(64);
    size_t zbytes = off;
    // rest (no init needed)
    hp.rep      = (int*)alloc(CN * sizeof(int));
    hp.sel      = (int*)alloc(MAX_DET * sizeof(int));
    hp.count_g  = (int*)alloc(64);
    hp.cand     = (float*)alloc(CAND_CAP * sizeof(float));

    hipMemsetAsync(hp.surv, 0, zbytes, stream);
    kR<<<NCLS * NCHUNK, 256, 0, stream>>>(hp);   // 512 blocks
    kG<<<CN / 256, 256, 0, stream>>>(hp);        // 128 blocks
    kO<<<MAX_DET + 1, 256, 0, stream>>>(hp);     // 101 blocks
}

// Round 7
// 135.194 us; speedup vs baseline: 2.5599x; 1.4726x over previous
//
#include <hip/hip_runtime.h>
#include <stdint.h>

#define N_ANCH 4096
#define NCLS 8
#define CN (N_ANCH * NCLS)
#define SCORE_TH 0.5f
#define IOU_TH 0.5f
#define KSEL 11
#define MAX_DET 100
#define CAND_CAP 4096
#define TILE 128
#define TPC (N_ANCH / TILE)          // 32
#define NTRI (TPC * (TPC + 1) / 2)   // 528 triangular tiles per class

struct Params {
    const float* boxes; const float* cls; const float* poses; const float* conf;
    int* validList; int* mVal; int* minRank;
    int* surv; int* hist; int* blockCnt; int* gcnt;
    int* rep; int* sel; int* count_g; float* cand;
    float* out;
};

__device__ __forceinline__ float area_f(float4 b) {
    return (b.z - b.x + 1.0f) * (b.w - b.y + 1.0f);
}

__device__ __forceinline__ float iou_f(float4 a, float areaA, float4 b, float areaB) {
    float x1 = fmaxf(a.x, b.x);
    float y1 = fmaxf(a.y, b.y);
    float x2 = fminf(a.z, b.z);
    float y2 = fminf(a.w, b.w);
    float wid = x2 - x1 + 1.0f;
    float hei = y2 - y1 + 1.0f;
    float inter = wid * hei;
    float den = areaA + areaB - inter;
    float ov = (den == 0.0f) ? 0.0f : (inter / den);
    if (wid <= 0.0f || hei <= 0.0f) ov = 0.0f;
    return ov;
}

// kS: 8 blocks (one per class). Single-pass ordered valid-list build
// (ballot all 16 chunks -> LDS, one-thread prefix, scatter) + all zero-init
// (surv, minRank=INF, hist, blockCnt, gcnt). Replaces memset dispatch.
__global__ void __launch_bounds__(256) kS(Params p) {
    const int c = blockIdx.x;
    const int tid = threadIdx.x;
    const int lane = tid & 63, w = tid >> 6;
    const int cbase = c << 12;
    __shared__ unsigned long long smask[64];  // [16][4]
    __shared__ int sbase[16];

    for (int ch = 0; ch < 16; ch++) {
        int n = ch * 256 + tid;
        int flag = (p.cls[n * 8 + c] > SCORE_TH) ? 1 : 0;
        unsigned long long m = __ballot(flag);
        if (lane == 0) smask[ch * 4 + w] = m;
    }
    __syncthreads();
    if (tid == 0) {
        int run = 0;
        for (int ch = 0; ch < 16; ch++) {
            sbase[ch] = run;
            run += __popcll(smask[ch * 4]) + __popcll(smask[ch * 4 + 1]) +
                   __popcll(smask[ch * 4 + 2]) + __popcll(smask[ch * 4 + 3]);
        }
        p.mVal[c] = run;
    }
    __syncthreads();
    for (int ch = 0; ch < 16; ch++) {
        unsigned long long m = smask[ch * 4 + w];
        if ((m >> lane) & 1ull) {
            int rank = __popcll(m & ((1ull << lane) - 1ull));
            int wb = 0;
            for (int i = 0; i < w; i++) wb += __popcll(smask[ch * 4 + i]);
            p.validList[c * N_ANCH + sbase[ch] + wb + rank] = ch * 256 + tid;
        }
    }
    // zero-init this class's slices + (block 0) the small shared counters
    for (int i = tid; i < N_ANCH; i += 256) {
        p.surv[cbase + i] = 0;
        p.minRank[cbase + i] = 0x7FFFFFFF;
    }
    if (c == 0) {
        for (int i = tid; i < 1024; i += 256) p.hist[i] = 0;
        if (tid < 128) p.blockCnt[tid] = 0;
        if (tid == 0) *p.gcnt = 0;
    }
}

// kM: triangular tiled rep-matrix. Block = (class, i-tile, j-tile<=i-tile),
// 128 threads (one i-rank each), j-tile boxes staged in LDS, full-tile
// no-break min scan (unroll-4 -> pipelined LDS reads), one rare atomicMin.
__global__ void __launch_bounds__(128) kM(Params p) {
    int bid = blockIdx.x;
    int c = bid / NTRI;
    int t = bid - c * NTRI;
    int ci = (int)((sqrtf(8.0f * (float)t + 1.0f) - 1.0f) * 0.5f);
    while ((ci + 1) * (ci + 2) / 2 <= t) ci++;
    while (ci * (ci + 1) / 2 > t) ci--;
    int cj = t - ci * (ci + 1) / 2;
    int mc = p.mVal[c];
    int ib = ci * TILE, jb = cj * TILE;
    if (ib >= mc || jb >= mc) return;
    int tid = threadIdx.x;
    int cbase = c << 12;
    const int* vl = p.validList + cbase;
    const float4* boxes4 = (const float4*)p.boxes;
    __shared__ float4 sB[TILE];
    if (jb + tid < mc) {
        int vj = vl[jb + tid];
        sB[tid] = boxes4[vj * 8 + c];
    }
    __syncthreads();
    int i = ib + tid;
    if (i >= mc) return;
    int k = vl[i];
    float4 bk = boxes4[k * 8 + c];
    float ak = area_f(bk);
    int limit = min(TILE, mc - jb);
    if (ci == cj) limit = min(limit, tid);   // strictly j-rank < i-rank
    int lmin = 0x7FFFFFFF;
    #pragma unroll 4
    for (int r = 0; r < limit; r++) {
        float4 bj = sB[r];
        float ov = iou_f(bk, ak, bj, area_f(bj));
        if (ov > IOU_TH && r < lmin) lmin = r;
    }
    if (lmin != 0x7FFFFFFF) atomicMin(&p.minRank[cbase + i], jb + lmin);
}

// kF: finalize rep + surv (first-setter also bumps blockCnt + score hist).
__global__ void __launch_bounds__(256) kF(Params p) {
    int t = blockIdx.x * 256 + threadIdx.x;
    int c = t >> 12;
    int i = t & (N_ANCH - 1);   // rank
    if (i >= p.mVal[c]) return;
    int cbase = c << 12;
    const int* vl = p.validList + cbase;
    const float4* boxes4 = (const float4*)p.boxes;
    int k = vl[i];
    int mr = p.minRank[t];
    if (mr > i) mr = i;         // self
    int ja = vl[mr];
    p.rep[cbase + k] = ja;
    if (mr < i) {
        float4 bk = boxes4[k * 8 + c];
        float4 bj = boxes4[ja * 8 + c];
        float ov = iou_f(bk, area_f(bk), bj, area_f(bj));
        float bcv = (1.0f - ov) * p.conf[k * 8 + c];
        if (bcv != 0.0f) {
            int old = atomicExch(&p.surv[cbase + ja], 1);
            if (old == 0) {
                atomicAdd(&p.blockCnt[(cbase + ja) >> 8], 1);
                unsigned bits = __float_as_uint(p.cls[ja * 8 + c]);
                int bb = (int)((bits - 0x3F000000u) >> 13);
                int bkt = bb < 0 ? 0 : (bb > 1023 ? 1023 : bb);
                atomicAdd(&p.hist[bkt], 1);
            }
        }
    }
}

// kG: 128 blocks. Redundant chunk-prefix + histogram threshold, ordered
// sel-write of first 100 survivors (flat order), candidate score gather.
__global__ void __launch_bounds__(256) kG(Params p) {
    const int bid = blockIdx.x;
    const int tid = threadIdx.x;
    const int lane = tid & 63, w = tid >> 6;
    __shared__ int sCnt[128];
    __shared__ int sSfx[256];
    __shared__ int s_misc[8];

    if (tid == 0) s_misc[0] = 0;  // thrB
    if (tid < 128) sCnt[tid] = p.blockCnt[tid];
    int part = p.hist[4 * tid] + p.hist[4 * tid + 1] +
               p.hist[4 * tid + 2] + p.hist[4 * tid + 3];
    sSfx[tid] = part;
    __syncthreads();
    if (tid == 0) {
        int run = 0, myoff = 0;
        for (int i = 0; i < 128; i++) {
            if (i == bid) myoff = run;
            run += sCnt[i];
        }
        s_misc[1] = run;    // total survivor count
        s_misc[2] = myoff;  // this chunk's base offset
        if (bid == 0) *p.count_g = run;
        int run2 = 0;
        for (int i = 255; i >= 0; i--) { int v = sSfx[i]; sSfx[i] = run2; run2 += v; }
    }
    __syncthreads();
    int count = s_misc[1];
    int target = count < MAX_DET ? count : MAX_DET;
    int S = sSfx[tid];
    int found = -1;
    for (int b = 4 * tid + 3; b >= 4 * tid; b--) {
        S += p.hist[b];
        if (found < 0 && S >= target) found = b;
    }
    if (found >= 0) atomicMax(&s_misc[0], found);
    __syncthreads();
    int t0 = s_misc[0];

    // ordered gather
    int q = bid * 256 + tid;
    int c = q >> 12, n = q & (N_ANCH - 1);
    int flag = p.surv[q] != 0;
    unsigned long long mask = __ballot(flag);
    if (lane == 0) s_misc[4 + w] = __popcll(mask);
    __syncthreads();
    int rank = __popcll(mask & ((1ull << lane) - 1ull));
    int wbase = 0;
    for (int i = 0; i < w; i++) wbase += s_misc[4 + i];
    int idx = s_misc[2] + wbase + rank;
    if (flag && idx < MAX_DET) p.sel[idx] = q;
    if (flag) {
        float sc = p.cls[n * 8 + c];
        unsigned bits = __float_as_uint(sc);
        int bb = (int)((bits - 0x3F000000u) >> 13);
        int bkt = bb < 0 ? 0 : (bb > 1023 ? 1023 : bb);
        if (bkt >= t0) {
            int id = atomicAdd(p.gcnt, 1);
            if (id < CAND_CAP) p.cand[id] = sc;
        }
    }
}

// kO: block 0 = bitonic sort of candidate scores -> top-100 scores;
// blocks 1..100 = per-slot cluster gather + KSEL selection + averages.
__global__ void __launch_bounds__(256) kO(Params p) {
    const int bid = blockIdx.x;
    const int tid = threadIdx.x;
    const int lane = tid & 63, w = tid >> 6;
    __shared__ __align__(16) unsigned char SMEM[32768];
    __shared__ int s_misc[8];
    __shared__ int s_ksel[KSEL];
    __shared__ unsigned long long s_red[5];
    const float4* boxes4 = (const float4*)p.boxes;

    if (bid == 0) {
        float* s = (float*)SMEM;
        int cc = *p.gcnt; if (cc > CAND_CAP) cc = CAND_CAP;
        int count = *p.count_g;
        int n = 128; while (n < cc) n <<= 1;
        for (int i = tid; i < n; i += 256) s[i] = (i < cc) ? -p.cand[i] : 1e38f;
        __syncthreads();
        for (int kk = 2; kk <= n; kk <<= 1) {
            for (int jj = kk >> 1; jj > 0; jj >>= 1) {
                for (int i = tid; i < n; i += 256) {
                    int ixj = i ^ jj;
                    if (ixj > i) {
                        float a = s[i], b2 = s[ixj];
                        bool up = ((i & kk) == 0);
                        if (up ? (a > b2) : (a < b2)) { s[i] = b2; s[ixj] = a; }
                    }
                }
                __syncthreads();
            }
        }
        if (tid < MAX_DET) p.out[tid] = (tid < count) ? -s[tid] : -1.0f;
    } else {
        int s = bid - 1;
        int count = *p.count_g;
        if (s >= count) {
            if (tid == 0) { p.out[100 + s] = -1.0f; p.out[1400 + s] = -1.0f; }
            if (tid < 12) p.out[200 + s * 12 + tid] = -1.0f;
            if (tid >= 16 && tid < 20) p.out[1500 + s * 4 + (tid - 16)] = -1.0f;
        } else {
            int sp = p.sel[s];
            int c = sp >> 12;
            int r = sp & (N_ANCH - 1);
            int cbase = c << 12;
            unsigned long long* keyArr = (unsigned long long*)SMEM;  // 4096 x 8 B
            if (tid == 0) s_misc[0] = 0;  // nm
            __syncthreads();
            float4 br = boxes4[r * 8 + c];
            float ar = area_f(br);
            for (int k = tid; k < N_ANCH; k += 256) {
                if (k != r && p.cls[k * 8 + c] > SCORE_TH && p.rep[cbase + k] == r) {
                    float4 bkk = boxes4[k * 8 + c];
                    float ov = iou_f(br, ar, bkk, area_f(bkk));
                    float bcv = (1.0f - ov) * p.conf[k * 8 + c];
                    if (bcv != 0.0f) {
                        int id = atomicAdd(&s_misc[0], 1);
                        keyArr[id] = ((unsigned long long)__float_as_uint(bcv) << 32) | (unsigned)k;
                    }
                }
            }
            __syncthreads();
            int nm = s_misc[0];
            int dn = nm < KSEL ? nm : KSEL;
            unsigned long long lastBest = ~0ull;
            for (int j = 0; j < dn; j++) {
                unsigned long long bk = ~0ull;
                for (int i = tid; i < nm; i += 256) {
                    unsigned long long v = keyArr[i];
                    if (v == lastBest) { keyArr[i] = ~0ull; v = ~0ull; }
                    if (v < bk) bk = v;
                }
                for (int off = 32; off > 0; off >>= 1) {
                    unsigned long long o = __shfl_down(bk, off);
                    if (o < bk) bk = o;
                }
                if (lane == 0) s_red[w] = bk;
                __syncthreads();
                if (tid == 0) {
                    unsigned long long B = s_red[0];
                    for (int q2 = 1; q2 < 4; q2++) if (s_red[q2] < B) B = s_red[q2];
                    s_red[4] = B;
                    s_ksel[j] = (int)(B & 0xFFFFFFFFull);
                }
                __syncthreads();
                lastBest = s_red[4];
            }
            float fdn = (float)(dn > 0 ? dn : 1);
            if (tid < 12) {
                float ssum = 0.0f;
                for (int j = 0; j < dn; j++) {
                    int k = s_ksel[j];
                    ssum += p.poses[(k * 8 + c) * 12 + tid];
                }
                p.out[200 + s * 12 + tid] = ssum / fdn;
            } else if (tid < 16) {
                int d = tid - 12;
                float ssum = 0.0f;
                for (int j = 0; j < dn; j++) {
                    int k = s_ksel[j];
                    const float* bb2 = (const float*)&boxes4[k * 8 + c];
                    ssum += bb2[d];
                }
                p.out[1500 + s * 4 + d] = ssum / fdn;
            } else if (tid == 16) {
                p.out[100 + s] = (float)c;
            } else if (tid == 17) {
                p.out[1400 + s] = (float)r;
            }
        }
    }
}

extern "C" void kernel_launch(void* const* d_in, const int* in_sizes, int n_in,
                              void* d_out, int out_size, void* d_ws, size_t ws_size,
                              hipStream_t stream) {
    Params hp;
    hp.boxes = (const float*)d_in[1];
    hp.cls   = (const float*)d_in[2];
    hp.poses = (const float*)d_in[3];
    hp.conf  = (const float*)d_in[4];
    hp.out   = (float*)d_out;

    char* ws = (char*)d_ws;
    size_t off = 0;
    auto alloc = [&](size_t bytes) {
        void* pp = ws + off;
        off += (bytes + 255) & ~(size_t)255;
        return pp;
    };
    hp.validList = (int*)alloc(CN * sizeof(int));
    hp.mVal      = (int*)alloc(64);
    hp.minRank   = (int*)alloc(CN * sizeof(int));
    hp.surv      = (int*)alloc(CN * sizeof(int));
    hp.hist      = (int*)alloc(1024 * sizeof(int));
    hp.blockCnt  = (int*)alloc(128 * sizeof(int));
    hp.gcnt      = (int*)alloc(64);
    hp.rep       = (int*)alloc(CN * sizeof(int));
    hp.sel       = (int*)alloc(MAX_DET * sizeof(int));
    hp.count_g   = (int*)alloc(64);
    hp.cand      = (float*)alloc(CAND_CAP * sizeof(float));

    kS<<<NCLS, 256, 0, stream>>>(hp);            // 8 blocks: validList + init
    kM<<<NCLS * NTRI, TILE, 0, stream>>>(hp);    // 4224 blocks: rep-matrix
    kF<<<CN / 256, 256, 0, stream>>>(hp);        // 128 blocks: finalize
    kG<<<CN / 256, 256, 0, stream>>>(hp);        // 128 blocks: prefix+gather
    kO<<<MAX_DET + 1, 256, 0, stream>>>(hp);     // 101 blocks: sort + output
}

// Round 8
// 121.539 us; speedup vs baseline: 2.8475x; 1.1124x over previous
//
#include <hip/hip_runtime.h>
#include <stdint.h>

#define N_ANCH 4096
#define NCLS 8
#define CN (N_ANCH * NCLS)
#define SCORE_TH 0.5f
#define IOU_TH 0.5f
#define KSEL 11
#define MAX_DET 100
#define CAND_CAP 4096
#define TI 128                        // i-rows per block
#define TJ 64                         // j-cols per block (LDS-staged)
#define JOBS_PER_CLASS 1056           // sum_{ci=0}^{31} (2*ci+2) = 32*33

struct Params {
    const float* boxes; const float* cls; const float* poses; const float* conf;
    int* validList; int* mVal; int* minRank;
    int* surv; int* hist; int* blockCnt; int* gcnt;
    int* rep; int* sel; int* count_g; float* cand;
    float* out;
};

__device__ __forceinline__ float area_f(float4 b) {
    return (b.z - b.x + 1.0f) * (b.w - b.y + 1.0f);
}

__device__ __forceinline__ float iou_f(float4 a, float areaA, float4 b, float areaB) {
    float x1 = fmaxf(a.x, b.x);
    float y1 = fmaxf(a.y, b.y);
    float x2 = fminf(a.z, b.z);
    float y2 = fminf(a.w, b.w);
    float wid = x2 - x1 + 1.0f;
    float hei = y2 - y1 + 1.0f;
    float inter = wid * hei;
    float den = areaA + areaB - inter;
    float ov = (den == 0.0f) ? 0.0f : (inter / den);
    if (wid <= 0.0f || hei <= 0.0f) ov = 0.0f;
    return ov;
}

// kS: 8 blocks (one per class). Single-pass ordered valid-list build
// (ballot all 16 chunks -> LDS, one-thread prefix, scatter) + all zero-init.
__global__ void __launch_bounds__(256) kS(Params p) {
    const int c = blockIdx.x;
    const int tid = threadIdx.x;
    const int lane = tid & 63, w = tid >> 6;
    const int cbase = c << 12;
    __shared__ unsigned long long smask[64];  // [16][4]
    __shared__ int sbase[16];

    for (int ch = 0; ch < 16; ch++) {
        int n = ch * 256 + tid;
        int flag = (p.cls[n * 8 + c] > SCORE_TH) ? 1 : 0;
        unsigned long long m = __ballot(flag);
        if (lane == 0) smask[ch * 4 + w] = m;
    }
    __syncthreads();
    if (tid == 0) {
        int run = 0;
        for (int ch = 0; ch < 16; ch++) {
            sbase[ch] = run;
            run += __popcll(smask[ch * 4]) + __popcll(smask[ch * 4 + 1]) +
                   __popcll(smask[ch * 4 + 2]) + __popcll(smask[ch * 4 + 3]);
        }
        p.mVal[c] = run;
    }
    __syncthreads();
    for (int ch = 0; ch < 16; ch++) {
        unsigned long long m = smask[ch * 4 + w];
        if ((m >> lane) & 1ull) {
            int rank = __popcll(m & ((1ull << lane) - 1ull));
            int wb = 0;
            for (int i = 0; i < w; i++) wb += __popcll(smask[ch * 4 + i]);
            p.validList[c * N_ANCH + sbase[ch] + wb + rank] = ch * 256 + tid;
        }
    }
    for (int i = tid; i < N_ANCH; i += 256) {
        p.surv[cbase + i] = 0;
        p.minRank[cbase + i] = 0x7FFFFFFF;
    }
    if (c == 0) {
        for (int i = tid; i < 1024; i += 256) p.hist[i] = 0;
        if (tid < 128) p.blockCnt[tid] = 0;
        if (tid == 0) *p.gcnt = 0;
    }
}

// kM: rep-matrix min-rank scan. Block = (class, i-tile of 128 rows, j-tile of
// 64 cols, triangular: jb < ib+TI). 64-col LDS stage (boxes + areas), one
// thread per row, full-tile no-break scan, division-free IoU>0.5 predicate
// (inter > 0.5*den, exact-equivalent for den>0 modulo half-ulp of fdiv).
__global__ void __launch_bounds__(128) kM(Params p) {
    int bid = blockIdx.x;
    int c = bid / JOBS_PER_CLASS;
    int t = bid - c * JOBS_PER_CLASS;
    int ci = (int)((sqrtf(4.0f * (float)t + 1.0f) - 1.0f) * 0.5f);
    while ((ci + 1) * (ci + 2) <= t) ci++;   // block start for ci: ci*(ci+1)
    while (ci * (ci + 1) > t) ci--;
    int jt = t - ci * (ci + 1);              // jt in [0, 2*ci+1]
    int mc = p.mVal[c];
    int ib = ci * TI, jb = jt * TJ;
    if (ib >= mc || jb >= mc) return;
    int tid = threadIdx.x;
    int cbase = c << 12;
    const int* vl = p.validList + cbase;
    const float4* boxes4 = (const float4*)p.boxes;
    __shared__ float4 sB[TJ];
    __shared__ float sA[TJ];
    if (tid < TJ && jb + tid < mc) {
        int vj = vl[jb + tid];
        float4 b = boxes4[vj * 8 + c];
        sB[tid] = b;
        sA[tid] = area_f(b);
    }
    __syncthreads();
    int i = ib + tid;
    if (i >= mc) return;
    int limit = min(TJ, i - jb);        // strictly j-rank < i-rank (diag partial)
    limit = min(limit, mc - jb);
    if (limit <= 0) return;
    int k = vl[i];
    float4 bk = boxes4[k * 8 + c];
    float ak = area_f(bk);
    int lmin = 0x7FFFFFFF;
    #pragma unroll 4
    for (int r = 0; r < limit; r++) {
        float4 bj = sB[r];
        float x1 = fmaxf(bk.x, bj.x);
        float y1 = fmaxf(bk.y, bj.y);
        float x2 = fminf(bk.z, bj.z);
        float y2 = fminf(bk.w, bj.w);
        float wid = x2 - x1 + 1.0f;
        float hei = y2 - y1 + 1.0f;
        float inter = wid * hei;
        float den = ak + sA[r] - inter;
        bool m = (wid > 0.0f) && (hei > 0.0f) && (inter > 0.5f * den);
        if (m && r < lmin) lmin = r;
    }
    if (lmin != 0x7FFFFFFF) atomicMin(&p.minRank[cbase + i], jb + lmin);
}

// kF: finalize rep + surv (first-setter also bumps blockCnt + score hist).
__global__ void __launch_bounds__(256) kF(Params p) {
    int t = blockIdx.x * 256 + threadIdx.x;
    int c = t >> 12;
    int i = t & (N_ANCH - 1);   // rank
    if (i >= p.mVal[c]) return;
    int cbase = c << 12;
    const int* vl = p.validList + cbase;
    const float4* boxes4 = (const float4*)p.boxes;
    int k = vl[i];
    int mr = p.minRank[t];
    if (mr > i) mr = i;         // self
    int ja = vl[mr];
    p.rep[cbase + k] = ja;
    if (mr < i) {
        float4 bk = boxes4[k * 8 + c];
        float4 bj = boxes4[ja * 8 + c];
        float ov = iou_f(bk, area_f(bk), bj, area_f(bj));
        float bcv = (1.0f - ov) * p.conf[k * 8 + c];
        if (bcv != 0.0f) {
            int old = atomicExch(&p.surv[cbase + ja], 1);
            if (old == 0) {
                atomicAdd(&p.blockCnt[(cbase + ja) >> 8], 1);
                unsigned bits = __float_as_uint(p.cls[ja * 8 + c]);
                int bb = (int)((bits - 0x3F000000u) >> 13);
                int bkt = bb < 0 ? 0 : (bb > 1023 ? 1023 : bb);
                atomicAdd(&p.hist[bkt], 1);
            }
        }
    }
}

// kG: 128 blocks. Redundant chunk-prefix + histogram threshold, ordered
// sel-write of first 100 survivors (flat order), candidate score gather.
__global__ void __launch_bounds__(256) kG(Params p) {
    const int bid = blockIdx.x;
    const int tid = threadIdx.x;
    const int lane = tid & 63, w = tid >> 6;
    __shared__ int sCnt[128];
    __shared__ int sSfx[256];
    __shared__ int s_misc[8];

    if (tid == 0) s_misc[0] = 0;  // thrB
    if (tid < 128) sCnt[tid] = p.blockCnt[tid];
    int part = p.hist[4 * tid] + p.hist[4 * tid + 1] +
               p.hist[4 * tid + 2] + p.hist[4 * tid + 3];
    sSfx[tid] = part;
    __syncthreads();
    if (tid == 0) {
        int run = 0, myoff = 0;
        for (int i = 0; i < 128; i++) {
            if (i == bid) myoff = run;
            run += sCnt[i];
        }
        s_misc[1] = run;    // total survivor count
        s_misc[2] = myoff;  // this chunk's base offset
        if (bid == 0) *p.count_g = run;
        int run2 = 0;
        for (int i = 255; i >= 0; i--) { int v = sSfx[i]; sSfx[i] = run2; run2 += v; }
    }
    __syncthreads();
    int count = s_misc[1];
    int target = count < MAX_DET ? count : MAX_DET;
    int S = sSfx[tid];
    int found = -1;
    for (int b = 4 * tid + 3; b >= 4 * tid; b--) {
        S += p.hist[b];
        if (found < 0 && S >= target) found = b;
    }
    if (found >= 0) atomicMax(&s_misc[0], found);
    __syncthreads();
    int t0 = s_misc[0];

    // ordered gather
    int q = bid * 256 + tid;
    int c = q >> 12, n = q & (N_ANCH - 1);
    int flag = p.surv[q] != 0;
    unsigned long long mask = __ballot(flag);
    if (lane == 0) s_misc[4 + w] = __popcll(mask);
    __syncthreads();
    int rank = __popcll(mask & ((1ull << lane) - 1ull));
    int wbase = 0;
    for (int i = 0; i < w; i++) wbase += s_misc[4 + i];
    int idx = s_misc[2] + wbase + rank;
    if (flag && idx < MAX_DET) p.sel[idx] = q;
    if (flag) {
        float sc = p.cls[n * 8 + c];
        unsigned bits = __float_as_uint(sc);
        int bb = (int)((bits - 0x3F000000u) >> 13);
        int bkt = bb < 0 ? 0 : (bb > 1023 ? 1023 : bb);
        if (bkt >= t0) {
            int id = atomicAdd(p.gcnt, 1);
            if (id < CAND_CAP) p.cand[id] = sc;
        }
    }
}

// kO: block 0 = bitonic sort of candidate scores -> top-100 scores;
// blocks 1..100 = per-slot cluster gather + KSEL selection + averages.
__global__ void __launch_bounds__(256) kO(Params p) {
    const int bid = blockIdx.x;
    const int tid = threadIdx.x;
    const int lane = tid & 63, w = tid >> 6;
    __shared__ __align__(16) unsigned char SMEM[32768];
    __shared__ int s_misc[8];
    __shared__ int s_ksel[KSEL];
    __shared__ unsigned long long s_red[5];
    const float4* boxes4 = (const float4*)p.boxes;

    if (bid == 0) {
        float* s = (float*)SMEM;
        int cc = *p.gcnt; if (cc > CAND_CAP) cc = CAND_CAP;
        int count = *p.count_g;
        int n = 128; while (n < cc) n <<= 1;
        for (int i = tid; i < n; i += 256) s[i] = (i < cc) ? -p.cand[i] : 1e38f;
        __syncthreads();
        for (int kk = 2; kk <= n; kk <<= 1) {
            for (int jj = kk >> 1; jj > 0; jj >>= 1) {
                for (int i = tid; i < n; i += 256) {
                    int ixj = i ^ jj;
                    if (ixj > i) {
                        float a = s[i], b2 = s[ixj];
                        bool up = ((i & kk) == 0);
                        if (up ? (a > b2) : (a < b2)) { s[i] = b2; s[ixj] = a; }
                    }
                }
                __syncthreads();
            }
        }
        if (tid < MAX_DET) p.out[tid] = (tid < count) ? -s[tid] : -1.0f;
    } else {
        int s = bid - 1;
        int count = *p.count_g;
        if (s >= count) {
            if (tid == 0) { p.out[100 + s] = -1.0f; p.out[1400 + s] = -1.0f; }
            if (tid < 12) p.out[200 + s * 12 + tid] = -1.0f;
            if (tid >= 16 && tid < 20) p.out[1500 + s * 4 + (tid - 16)] = -1.0f;
        } else {
            int sp = p.sel[s];
            int c = sp >> 12;
            int r = sp & (N_ANCH - 1);
            int cbase = c << 12;
            unsigned long long* keyArr = (unsigned long long*)SMEM;  // 4096 x 8 B
            if (tid == 0) s_misc[0] = 0;  // nm
            __syncthreads();
            float4 br = boxes4[r * 8 + c];
            float ar = area_f(br);
            for (int k = tid; k < N_ANCH; k += 256) {
                if (k != r && p.cls[k * 8 + c] > SCORE_TH && p.rep[cbase + k] == r) {
                    float4 bkk = boxes4[k * 8 + c];
                    float ov = iou_f(br, ar, bkk, area_f(bkk));
                    float bcv = (1.0f - ov) * p.conf[k * 8 + c];
                    if (bcv != 0.0f) {
                        int id = atomicAdd(&s_misc[0], 1);
                        keyArr[id] = ((unsigned long long)__float_as_uint(bcv) << 32) | (unsigned)k;
                    }
                }
            }
            __syncthreads();
            int nm = s_misc[0];
            int dn = nm < KSEL ? nm : KSEL;
            unsigned long long lastBest = ~0ull;
            for (int j = 0; j < dn; j++) {
                unsigned long long bk = ~0ull;
                for (int i = tid; i < nm; i += 256) {
                    unsigned long long v = keyArr[i];
                    if (v == lastBest) { keyArr[i] = ~0ull; v = ~0ull; }
                    if (v < bk) bk = v;
                }
                for (int off = 32; off > 0; off >>= 1) {
                    unsigned long long o = __shfl_down(bk, off);
                    if (o < bk) bk = o;
                }
                if (lane == 0) s_red[w] = bk;
                __syncthreads();
                if (tid == 0) {
                    unsigned long long B = s_red[0];
                    for (int q2 = 1; q2 < 4; q2++) if (s_red[q2] < B) B = s_red[q2];
                    s_red[4] = B;
                    s_ksel[j] = (int)(B & 0xFFFFFFFFull);
                }
                __syncthreads();
                lastBest = s_red[4];
            }
            float fdn = (float)(dn > 0 ? dn : 1);
            if (tid < 12) {
                float ssum = 0.0f;
                for (int j = 0; j < dn; j++) {
                    int k = s_ksel[j];
                    ssum += p.poses[(k * 8 + c) * 12 + tid];
                }
                p.out[200 + s * 12 + tid] = ssum / fdn;
            } else if (tid < 16) {
                int d = tid - 12;
                float ssum = 0.0f;
                for (int j = 0; j < dn; j++) {
                    int k = s_ksel[j];
                    const float* bb2 = (const float*)&boxes4[k * 8 + c];
                    ssum += bb2[d];
                }
                p.out[1500 + s * 4 + d] = ssum / fdn;
            } else if (tid == 16) {
                p.out[100 + s] = (float)c;
            } else if (tid == 17) {
                p.out[1400 + s] = (float)r;
            }
        }
    }
}

extern "C" void kernel_launch(void* const* d_in, const int* in_sizes, int n_in,
                              void* d_out, int out_size, void* d_ws, size_t ws_size,
                              hipStream_t stream) {
    Params hp;
    hp.boxes = (const float*)d_in[1];
    hp.cls   = (const float*)d_in[2];
    hp.poses = (const float*)d_in[3];
    hp.conf  = (const float*)d_in[4];
    hp.out   = (float*)d_out;

    char* ws = (char*)d_ws;
    size_t off = 0;
    auto alloc = [&](size_t bytes) {
        void* pp = ws + off;
        off += (bytes + 255) & ~(size_t)255;
        return pp;
    };
    hp.validList = (int*)alloc(CN * sizeof(int));
    hp.mVal      = (int*)alloc(64);
    hp.minRank   = (int*)alloc(CN * sizeof(int));
    hp.surv      = (int*)alloc(CN * sizeof(int));
    hp.hist      = (int*)alloc(1024 * sizeof(int));
    hp.blockCnt  = (int*)alloc(128 * sizeof(int));
    hp.gcnt      = (int*)alloc(64);
    hp.rep       = (int*)alloc(CN * sizeof(int));
    hp.sel       = (int*)alloc(MAX_DET * sizeof(int));
    hp.count_g   = (int*)alloc(64);
    hp.cand      = (float*)alloc(CAND_CAP * sizeof(float));

    kS<<<NCLS, 256, 0, stream>>>(hp);                    // 8 blocks
    kM<<<NCLS * JOBS_PER_CLASS, TI, 0, stream>>>(hp);    // 8448 blocks
    kF<<<CN / 256, 256, 0, stream>>>(hp);                // 128 blocks
    kG<<<CN / 256, 256, 0, stream>>>(hp);                // 128 blocks
    kO<<<MAX_DET + 1, 256, 0, stream>>>(hp);             // 101 blocks
}